// Round 5
// baseline (759.091 us; speedup 1.0000x reference)
//
#include <hip/hip_runtime.h>
#include <hip/hip_bf16.h>

// Problem constants (Mixtral attention prefill)
#define S_LEN 2048
#define HID 4096
#define NH 32
#define NKV 8
#define HD 128
#define NQKV 6144   // NH*HD + 2*NKV*HD

typedef unsigned short u16;
typedef unsigned int u32;
typedef __bf16 bf16x8 __attribute__((ext_vector_type(8)));
typedef float f32x4 __attribute__((ext_vector_type(4)));

__device__ __forceinline__ float bf2f(u16 u) {
    union { u32 i; float f; } x; x.i = ((u32)u) << 16; return x.f;
}
__device__ __forceinline__ u16 f2bf(float f) {
    union { float f; u32 i; } x; x.f = f;
    u32 r = x.i + 0x7fffu + ((x.i >> 16) & 1u);   // RNE
    return (u16)(r >> 16);
}
__device__ __forceinline__ u32 pack2(float a, float b) {
    return (u32)f2bf(a) | ((u32)f2bf(b) << 16);
}
// async global->LDS, 16 B per lane; LDS dest is wave-uniform base + lane*16
__device__ __forceinline__ void gld16(const u16* g, u16* l) {
    __builtin_amdgcn_global_load_lds(
        (const __attribute__((address_space(1))) u32*)g,
        (__attribute__((address_space(3))) u32*)l, 16, 0, 0);
}

// ---------------------------------------------------------------------------
// fp32 -> bf16 convert (8 elems/thread), n8 = n/8
// ---------------------------------------------------------------------------
__global__ __launch_bounds__(256) void cvt_f32_bf16(
    const float* __restrict__ src, u16* __restrict__ dst, int n8)
{
    int i = blockIdx.x * 256 + threadIdx.x;
    if (i >= n8) return;
    const float4* s = (const float4*)src + (size_t)i * 2;
    float4 x0 = s[0], x1 = s[1];
    uint4 p;
    p.x = pack2(x0.x, x0.y); p.y = pack2(x0.z, x0.w);
    p.z = pack2(x1.x, x1.y); p.w = pack2(x1.z, x1.w);
    *((uint4*)dst + i) = p;
}

// ---------------------------------------------------------------------------
// m97-style GEMM: C[M][N] = X[M][K] * W[N][K]^T, all bf16, fp32 acc.
// 128x128 tile, BK=32, global_load_lds width=16 staging. (unchanged, R4-good)
// ---------------------------------------------------------------------------
template <bool OUTBF16>
__global__ __launch_bounds__(256) void gemm128(
    const u16* __restrict__ X, const u16* __restrict__ W,
    void* __restrict__ C, int K, int ldc)
{
    __shared__ __align__(16) u16 As[128 * 32];
    __shared__ __align__(16) u16 Bs[128 * 32];

    const int tid  = threadIdx.x;
    const int w    = tid >> 6;
    const int lane = tid & 63;
    const int quad = lane >> 4;
    const int n16  = lane & 15;
    const int m0   = blockIdx.y * 128;
    const int n0   = blockIdx.x * 128;
    const int wr   = (w >> 1) * 64;
    const int wc   = (w & 1) * 64;

    const int c0 = tid;
    const int c1 = tid + 256;

    f32x4 acc[4][4] = {};

    for (int k0 = 0; k0 < K; k0 += 32) {
        __syncthreads();
        gld16(X + (size_t)(m0 + (c0 >> 2)) * K + k0 + (c0 & 3) * 8,
              As + (size_t)(w * 64) * 8);
        gld16(X + (size_t)(m0 + (c1 >> 2)) * K + k0 + (c1 & 3) * 8,
              As + (size_t)(256 + w * 64) * 8);
        gld16(W + (size_t)(n0 + (c0 >> 2)) * K + k0 + (c0 & 3) * 8,
              Bs + (size_t)(w * 64) * 8);
        gld16(W + (size_t)(n0 + (c1 >> 2)) * K + k0 + (c1 & 3) * 8,
              Bs + (size_t)(256 + w * 64) * 8);
        __syncthreads();

        bf16x8 a[4], b[4];
#pragma unroll
        for (int t = 0; t < 4; ++t) {
            a[t] = *reinterpret_cast<const bf16x8*>(As + (wr + t * 16 + n16) * 32 + quad * 8);
            b[t] = *reinterpret_cast<const bf16x8*>(Bs + (wc + t * 16 + n16) * 32 + quad * 8);
        }
#pragma unroll
        for (int mt = 0; mt < 4; ++mt)
#pragma unroll
            for (int nt = 0; nt < 4; ++nt)
                acc[mt][nt] = __builtin_amdgcn_mfma_f32_16x16x32_bf16(
                    a[mt], b[nt], acc[mt][nt], 0, 0, 0);
    }

#pragma unroll
    for (int mt = 0; mt < 4; ++mt) {
        const int row0 = m0 + wr + mt * 16 + quad * 4;
#pragma unroll
        for (int nt = 0; nt < 4; ++nt) {
            const int col = n0 + wc + nt * 16 + n16;
#pragma unroll
            for (int r = 0; r < 4; ++r) {
                if constexpr (OUTBF16)
                    ((u16*)C)[(size_t)(row0 + r) * ldc + col] = f2bf(acc[mt][nt][r]);
                else
                    ((float*)C)[(size_t)(row0 + r) * ldc + col] = acc[mt][nt][r];
            }
        }
    }
}

// ---------------------------------------------------------------------------
// Fallback GEMM (fp32 inputs, 64x64 tile) — used when ws is small.
// ---------------------------------------------------------------------------
template <bool XF32, bool OUTBF16>
__global__ __launch_bounds__(256) void gemm_bt(
    const void* __restrict__ Xv,
    const float* __restrict__ W0, int r1,
    const float* __restrict__ W1, int r2,
    const float* __restrict__ W2,
    void* __restrict__ C, int K, int ldc)
{
    __shared__ u16 Xs[64][48];
    __shared__ u16 Ws[64][48];

    const int tid  = threadIdx.x;
    const int w    = tid >> 6;
    const int lane = tid & 63;
    const int m0   = blockIdx.y * 64;
    const int n0   = blockIdx.x * 64;

    const int sr = tid >> 2;
    const int sc = (tid & 3) * 8;

    const float* xrow32 = nullptr;
    const u16*   xrow16 = nullptr;
    if constexpr (XF32) xrow32 = (const float*)Xv + (size_t)(m0 + sr) * K;
    else                xrow16 = (const u16*)Xv + (size_t)(m0 + sr) * K;

    const int wr = n0 + sr;
    const float* wrow;
    if (wr < r1)      wrow = W0 + (size_t)wr * K;
    else if (wr < r2) wrow = W1 + (size_t)(wr - r1) * K;
    else              wrow = W2 + (size_t)(wr - r2) * K;

    f32x4 acc[4] = {};
    const int mrow = w * 16 + (lane & 15);
    const int nrow = lane & 15;
    const int kq   = (lane >> 4) * 8;

    for (int k0 = 0; k0 < K; k0 += 32) {
        __syncthreads();
        if constexpr (XF32) {
            float4 x0 = *reinterpret_cast<const float4*>(xrow32 + k0 + sc);
            float4 x1 = *reinterpret_cast<const float4*>(xrow32 + k0 + sc + 4);
            uint4 p;
            p.x = pack2(x0.x, x0.y); p.y = pack2(x0.z, x0.w);
            p.z = pack2(x1.x, x1.y); p.w = pack2(x1.z, x1.w);
            *reinterpret_cast<uint4*>(&Xs[sr][sc]) = p;
        } else {
            *reinterpret_cast<uint4*>(&Xs[sr][sc]) =
                *reinterpret_cast<const uint4*>(xrow16 + k0 + sc);
        }
        {
            float4 w0v = *reinterpret_cast<const float4*>(wrow + k0 + sc);
            float4 w1v = *reinterpret_cast<const float4*>(wrow + k0 + sc + 4);
            uint4 p;
            p.x = pack2(w0v.x, w0v.y); p.y = pack2(w0v.z, w0v.w);
            p.z = pack2(w1v.x, w1v.y); p.w = pack2(w1v.z, w1v.w);
            *reinterpret_cast<uint4*>(&Ws[sr][sc]) = p;
        }
        __syncthreads();
        bf16x8 a = *reinterpret_cast<const bf16x8*>(&Xs[mrow][kq]);
#pragma unroll
        for (int t = 0; t < 4; ++t) {
            bf16x8 b = *reinterpret_cast<const bf16x8*>(&Ws[t * 16 + nrow][kq]);
            acc[t] = __builtin_amdgcn_mfma_f32_16x16x32_bf16(a, b, acc[t], 0, 0, 0);
        }
    }

    const int mb = m0 + w * 16 + ((lane >> 4) << 2);
#pragma unroll
    for (int t = 0; t < 4; ++t) {
        const int col = n0 + t * 16 + (lane & 15);
#pragma unroll
        for (int i = 0; i < 4; ++i) {
            if constexpr (OUTBF16)
                ((u16*)C)[(size_t)(mb + i) * ldc + col] = f2bf(acc[t][i]);
            else
                ((float*)C)[(size_t)(mb + i) * ldc + col] = acc[t][i];
        }
    }
}

// ---------------------------------------------------------------------------
// RoPE (half-split, theta=1e6) on q,k; Q pre-scaled by 1/sqrt(HD).
// V is NOT handled here anymore (transpose_v reads it from qkv directly).
// ---------------------------------------------------------------------------
__global__ __launch_bounds__(256) void rope_kernel(
    const u16* __restrict__ qkv, const int* __restrict__ pos,
    u16* __restrict__ qb, u16* __restrict__ kb)
{
    const int n   = blockIdx.x;
    const int tid = threadIdx.x;
    const float scale = 0.08838834764831845f;
    __shared__ float cs[64], sn[64];
    if (tid < 64) {
        float p   = (float)pos[n];
        float inv = powf(1.0e6f, -(float)tid / 64.0f);
        float f   = p * inv;
        cs[tid] = cosf(f);
        sn[tid] = sinf(f);
    }
    __syncthreads();
    const u16* row = qkv + (size_t)n * NQKV;

    for (int i = tid; i < NH * 64; i += 256) {
        int h = i >> 6, j = i & 63;
        float x1 = bf2f(row[h * HD + j]), x2 = bf2f(row[h * HD + j + 64]);
        size_t base = ((size_t)h * S_LEN + n) * HD;
        qb[base + j]      = f2bf((x1 * cs[j] - x2 * sn[j]) * scale);
        qb[base + j + 64] = f2bf((x2 * cs[j] + x1 * sn[j]) * scale);
    }
    for (int i = tid; i < NKV * 64; i += 256) {
        int g = i >> 6, j = i & 63;
        const u16* kr = row + NH * HD + g * HD;
        float x1 = bf2f(kr[j]), x2 = bf2f(kr[j + 64]);
        size_t base = ((size_t)g * S_LEN + n) * HD;
        kb[base + j]      = f2bf(x1 * cs[j] - x2 * sn[j]);
        kb[base + j + 64] = f2bf(x2 * cs[j] + x1 * sn[j]);
    }
}

// ---------------------------------------------------------------------------
// V transpose: vt[g][d][n] = qkv[n][5120 + g*128 + d].  Tiled via LDS.
// grid (32 token-tiles, 8 groups) x 256 threads.
// ---------------------------------------------------------------------------
__global__ __launch_bounds__(256) void transpose_v(
    const u16* __restrict__ qkv, u16* __restrict__ vt)
{
    __shared__ u16 T[64][132];   // stride 132 u16: 8B-aligned rows, low conflict
    const int tid = threadIdx.x;
    const int g   = blockIdx.y;
    const int n0  = blockIdx.x * 64;

    // read 64 tokens x 128 dims (uint2 = 4 u16 chunks; 2048 chunks, 8/thread)
#pragma unroll
    for (int i = 0; i < 8; ++i) {
        int c = tid + 256 * i;
        int tok = c >> 5, d0 = (c & 31) * 4;
        *reinterpret_cast<uint2*>(&T[tok][d0]) =
            *reinterpret_cast<const uint2*>(
                qkv + (size_t)(n0 + tok) * NQKV + NH * HD + NKV * HD + g * HD + d0);
    }
    __syncthreads();
    // write vt rows: chunk = 8 tokens x 1 dim (1024 chunks, 4/thread)
#pragma unroll
    for (int i = 0; i < 4; ++i) {
        int c = tid + 256 * i;
        int d = c >> 3, t0 = (c & 7) * 8;
        u16 tmp[8];
#pragma unroll
        for (int j = 0; j < 8; ++j) tmp[j] = T[t0 + j][d];
        *reinterpret_cast<uint4*>(
            vt + (size_t)g * HD * S_LEN + (size_t)d * S_LEN + n0 + t0) =
            *reinterpret_cast<uint4*>(tmp);
    }
}

// ---------------------------------------------------------------------------
// MFMA flash attention v2 (causal GQA, merged group).
// Block = (kv group g, 32 queries); 4 waves = the 4 query heads of g, all
// sharing the staged K/V tiles. K-tile = 64 keys.
//   QK^T: A=Q[32q], B=K^T from Ks (key-major, stride 136: 2-way free)
//   PV:   A=P (LDS roundtrip, per-wave region), B=V from Vt (dim-major,
//         stride 72: 2-way free), pre-transposed in global (vt).
// LDS total 54272 B -> 2 blocks/CU; grid 512 blocks = 2/CU for latency hiding.
// ---------------------------------------------------------------------------
__global__ __launch_bounds__(256) void attn_mfma2(
    const u16* __restrict__ qb, const u16* __restrict__ kb,
    const u16* __restrict__ vt, u16* __restrict__ ao)
{
    __shared__ u16 Ks[64][136];     // 17408 B
    __shared__ u16 Vs[128][72];     // 18432 B
    __shared__ u16 Ps[4][32][72];   // 18432 B

    const int tid  = threadIdx.x;
    const int w    = tid >> 6;
    const int lane = tid & 63;
    const int quad = lane >> 4;
    const int n16  = lane & 15;
    const int g    = blockIdx.y;
    const int h    = g * 4 + w;          // head = g*M + m (reference grouping)
    const int q0   = blockIdx.x * 32;

    // Q A-frags: 2 m-tiles x 4 k-steps (qb pre-scaled by 1/sqrt(HD))
    bf16x8 qf[2][4];
#pragma unroll
    for (int mt = 0; mt < 2; ++mt) {
        const u16* qrow = qb + ((size_t)h * S_LEN + q0 + mt * 16 + n16) * HD;
#pragma unroll
        for (int s = 0; s < 4; ++s)
            qf[mt][s] = *reinterpret_cast<const bf16x8*>(qrow + s * 32 + quad * 8);
    }

    f32x4 of[2][8] = {};
    float mrow[2][4], lrow[2][4];
#pragma unroll
    for (int mt = 0; mt < 2; ++mt)
#pragma unroll
        for (int r = 0; r < 4; ++r) { mrow[mt][r] = -1e30f; lrow[mt][r] = 0.0f; }

    const int ntiles = (q0 >> 6) + 1;
    for (int kt = 0; kt < ntiles; ++kt) {
        const int k0 = kt * 64;
        __syncthreads();
        // ---- stage K tile: 64 keys x 128 dims, b128 writes (2-way free) ----
#pragma unroll
        for (int i = 0; i < 4; ++i) {
            int c = tid + 256 * i;
            int key = c >> 4, d0 = (c & 15) * 8;
            *reinterpret_cast<uint4*>(&Ks[key][d0]) =
                *reinterpret_cast<const uint4*>(
                    kb + ((size_t)g * S_LEN + k0 + key) * HD + d0);
        }
        // ---- stage V tile (already transposed in global): 128 d x 64 keys --
#pragma unroll
        for (int i = 0; i < 4; ++i) {
            int c = tid + 256 * i;
            int d = c >> 3, koff = (c & 7) * 8;
            *reinterpret_cast<uint4*>(&Vs[d][koff]) =
                *reinterpret_cast<const uint4*>(
                    vt + (size_t)g * HD * S_LEN + (size_t)d * S_LEN + k0 + koff);
        }
        __syncthreads();

        // ---- QK^T: 32 MFMA -> scores 32q x 64k ----
        f32x4 sc[2][4] = {};
#pragma unroll
        for (int s = 0; s < 4; ++s) {
            bf16x8 b[4];
#pragma unroll
            for (int nt = 0; nt < 4; ++nt)
                b[nt] = *reinterpret_cast<const bf16x8*>(
                    &Ks[nt * 16 + n16][s * 32 + quad * 8]);
#pragma unroll
            for (int mt = 0; mt < 2; ++mt)
#pragma unroll
                for (int nt = 0; nt < 4; ++nt)
                    sc[mt][nt] = __builtin_amdgcn_mfma_f32_16x16x32_bf16(
                        qf[mt][s], b[nt], sc[mt][nt], 0, 0, 0);
        }

        // ---- causal mask (diagonal tile only) ----
        if (kt == ntiles - 1) {
#pragma unroll
            for (int mt = 0; mt < 2; ++mt) {
                const int qbase = q0 + mt * 16 + quad * 4;
#pragma unroll
                for (int nt = 0; nt < 4; ++nt) {
                    int key = k0 + nt * 16 + n16;
#pragma unroll
                    for (int r = 0; r < 4; ++r)
                        if (key > qbase + r) sc[mt][nt][r] = -1e30f;
                }
            }
        }

        // ---- online softmax; P -> per-wave LDS (bf16) ----
#pragma unroll
        for (int mt = 0; mt < 2; ++mt) {
#pragma unroll
            for (int r = 0; r < 4; ++r) {
                float mx = fmaxf(fmaxf(sc[mt][0][r], sc[mt][1][r]),
                                 fmaxf(sc[mt][2][r], sc[mt][3][r]));
                mx = fmaxf(mx, __shfl_xor(mx, 1));
                mx = fmaxf(mx, __shfl_xor(mx, 2));
                mx = fmaxf(mx, __shfl_xor(mx, 4));
                mx = fmaxf(mx, __shfl_xor(mx, 8));
                float mnew  = fmaxf(mrow[mt][r], mx);
                float alpha = __expf(mrow[mt][r] - mnew);
                float ls = 0.0f;
#pragma unroll
                for (int nt = 0; nt < 4; ++nt) {
                    float p = __expf(sc[mt][nt][r] - mnew);
                    Ps[w][mt * 16 + quad * 4 + r][nt * 16 + n16] = f2bf(p);
                    ls += p;
                }
                ls += __shfl_xor(ls, 1);
                ls += __shfl_xor(ls, 2);
                ls += __shfl_xor(ls, 4);
                ls += __shfl_xor(ls, 8);
                lrow[mt][r] = lrow[mt][r] * alpha + ls;
                mrow[mt][r] = mnew;
#pragma unroll
                for (int dt = 0; dt < 8; ++dt) of[mt][dt][r] *= alpha;
            }
        }
        __threadfence_block();   // drain P writes before same-wave A-frag reads

        // ---- PV: 32 MFMA, accumulate O (32q x 128d per wave) ----
#pragma unroll
        for (int s2 = 0; s2 < 2; ++s2) {
            bf16x8 a[2];
#pragma unroll
            for (int mt = 0; mt < 2; ++mt)
                a[mt] = *reinterpret_cast<const bf16x8*>(
                    &Ps[w][mt * 16 + n16][s2 * 32 + quad * 8]);
#pragma unroll
            for (int dt = 0; dt < 8; ++dt) {
                bf16x8 b = *reinterpret_cast<const bf16x8*>(
                    &Vs[dt * 16 + n16][s2 * 32 + quad * 8]);
#pragma unroll
                for (int mt = 0; mt < 2; ++mt)
                    of[mt][dt] = __builtin_amdgcn_mfma_f32_16x16x32_bf16(
                        a[mt], b, of[mt][dt], 0, 0, 0);
            }
        }
    }

    // ---- epilogue ----
#pragma unroll
    for (int mt = 0; mt < 2; ++mt) {
#pragma unroll
        for (int r = 0; r < 4; ++r) {
            float inv = 1.0f / lrow[mt][r];
            u16* dst = ao + (size_t)(q0 + mt * 16 + quad * 4 + r) * (NH * HD)
                       + h * HD + n16;
#pragma unroll
            for (int dt = 0; dt < 8; ++dt)
                dst[dt * 16] = f2bf(of[mt][dt][r] * inv);
        }
    }
}

// ---------------------------------------------------------------------------
// Fast-path workspace overlay (bytes), peak 92,274,688:
//   hb   [2048][4096] bf16 @ 0           -> reused as qb after gemm1
//   wqkv [6144][4096] bf16 @ 16,777,216  -> dead after gemm1:
//        ao @ 16,777,216 | kb @ 33,554,432 | vt @ 37,748,736 (4 MB)
//   wo_b [4096][4096] bf16 @ 41,943,040  (converted after rope+transpose)
//   qkv  [2048][6144] bf16 @ 67,108,864  -> dead after rope+transpose
// ---------------------------------------------------------------------------
extern "C" void kernel_launch(void* const* d_in, const int* in_sizes, int n_in,
                              void* d_out, int out_size, void* d_ws, size_t ws_size,
                              hipStream_t stream)
{
    const float* h   = (const float*)d_in[0];
    const int*   pos = (const int*)d_in[1];
    const float* wq  = (const float*)d_in[2];
    const float* wk  = (const float*)d_in[3];
    const float* wv  = (const float*)d_in[4];
    const float* wo  = (const float*)d_in[5];

    char* ws = (char*)d_ws;

    if (ws_size >= 92274688ull) {
        u16* hb     = (u16*)(ws);
        u16* wqkv_b = (u16*)(ws + 16777216);
        u16* ao     = (u16*)(ws + 16777216);
        u16* kb     = (u16*)(ws + 33554432);
        u16* vt     = (u16*)(ws + 37748736);
        u16* wo_b   = (u16*)(ws + 41943040);
        u16* qkv    = (u16*)(ws + 67108864);
        u16* qb     = hb;

        cvt_f32_bf16<<<4096, 256, 0, stream>>>(h, hb, 1048576);
        cvt_f32_bf16<<<8192, 256, 0, stream>>>(wq, wqkv_b, 2097152);
        cvt_f32_bf16<<<2048, 256, 0, stream>>>(wk, wqkv_b + 16777216, 524288);
        cvt_f32_bf16<<<2048, 256, 0, stream>>>(wv, wqkv_b + 20971520, 524288);

        gemm128<true><<<dim3(NQKV / 128, S_LEN / 128), 256, 0, stream>>>(
            hb, wqkv_b, qkv, HID, NQKV);
        rope_kernel<<<S_LEN, 256, 0, stream>>>(qkv, pos, qb, kb);
        transpose_v<<<dim3(S_LEN / 64, NKV), 256, 0, stream>>>(qkv, vt);
        cvt_f32_bf16<<<8192, 256, 0, stream>>>(wo, wo_b, 2097152);
        attn_mfma2<<<dim3(S_LEN / 32, NKV), 256, 0, stream>>>(qb, kb, vt, ao);
        gemm128<false><<<dim3(HID / 128, S_LEN / 128), 256, 0, stream>>>(
            ao, wo_b, d_out, NH * HD, HID);
    } else {
        // ---- fallback (64 MB layout) ----
        u16* qkv = (u16*)(ws);
        u16* qb  = (u16*)(ws + 25165824);
        u16* kb  = (u16*)(ws + 41943040);
        u16* vt  = (u16*)(ws + 46137344);
        u16* ao  = (u16*)(ws + 50331648);

        dim3 g1(NQKV / 64, S_LEN / 64);
        gemm_bt<true, true><<<g1, 256, 0, stream>>>(
            h, wq, NH * HD, wk, NH * HD + NKV * HD, wv, qkv, HID, NQKV);
        rope_kernel<<<S_LEN, 256, 0, stream>>>(qkv, pos, qb, kb);
        transpose_v<<<dim3(S_LEN / 64, NKV), 256, 0, stream>>>(qkv, vt);
        attn_mfma2<<<dim3(S_LEN / 32, NKV), 256, 0, stream>>>(qb, kb, vt, ao);
        dim3 g2(HID / 64, S_LEN / 64);
        gemm_bt<false, false><<<g2, 256, 0, stream>>>(
            ao, wo, HID, wo, HID, wo, d_out, NH * HD, HID);
    }
}